// Round 10
// baseline (724.097 us; speedup 1.0000x reference)
//
#include <hip/hip_runtime.h>
#include <hip/hip_bf16.h>

#define Dd 1024
#define Hh 4096
#define Ee 8
#define Tt 4096   // tokens = 2*2048
#define Kk 2

typedef __attribute__((ext_vector_type(8))) short short8;
typedef __attribute__((ext_vector_type(4))) float f32x4;

__device__ __forceinline__ unsigned short f2bf_bits(float f) {
  unsigned u = __builtin_bit_cast(unsigned, f);
  u += 0x7FFFu + ((u >> 16) & 1u);   // RNE (finite values)
  return (unsigned short)(u >> 16);
}

__device__ __forceinline__ void glds16(const void* g, void* l) {
  __builtin_amdgcn_global_load_lds(
      (const __attribute__((address_space(1))) unsigned int*)g,
      (__attribute__((address_space(3))) unsigned int*)l, 16, 0, 0);
}

// ---------------- fp32 -> bf16 conversion (vectorized) ----------------
__global__ __launch_bounds__(256) void cvt_kernel(const float* __restrict__ src,
                                                  unsigned short* __restrict__ dst, int n4) {
  int i = blockIdx.x * blockDim.x + threadIdx.x;
  int stride = gridDim.x * blockDim.x;
  for (; i < n4; i += stride) {
    float4 v = reinterpret_cast<const float4*>(src)[i];
    ushort4 o;
    o.x = f2bf_bits(v.x);
    o.y = f2bf_bits(v.y);
    o.z = f2bf_bits(v.z);
    o.w = f2bf_bits(v.w);
    reinterpret_cast<ushort4*>(dst)[i] = o;
  }
}

// ---------------- router: softmax + top-2 + expert lists + fused token gather ----------------
__global__ __launch_bounds__(256) void router_kernel(
    const float* __restrict__ x, const float* __restrict__ Wr, const float* __restrict__ br,
    int* __restrict__ cnt, int* __restrict__ list, float* __restrict__ g2,
    unsigned short* __restrict__ xg) {
  int t = blockIdx.x * 4 + (threadIdx.x >> 6);
  int lane = threadIdx.x & 63;
  const float* xr = x + (size_t)t * Dd;
  float pe[Ee];
#pragma unroll
  for (int e = 0; e < Ee; e++) pe[e] = 0.f;
  for (int d = lane; d < Dd; d += 64) {
    float xv = xr[d];
#pragma unroll
    for (int e = 0; e < Ee; e++) pe[e] += xv * Wr[e * Dd + d];
  }
#pragma unroll
  for (int e = 0; e < Ee; e++) {
    float v = pe[e];
#pragma unroll
    for (int s = 32; s > 0; s >>= 1) v += __shfl_xor(v, s);
    pe[e] = v + br[e];
  }
  int e0 = 0, e1 = 0, p0 = 0, p1 = 0;
  if (lane == 0) {
    float mx = pe[0];
#pragma unroll
    for (int e = 1; e < Ee; e++) mx = fmaxf(mx, pe[e]);
    float g[Ee];
    float sum = 0.f;
#pragma unroll
    for (int e = 0; e < Ee; e++) { g[e] = expf(pe[e] - mx); sum += g[e]; }
    float inv = 1.0f / sum;
    float g0v = g[0];
#pragma unroll
    for (int e = 1; e < Ee; e++) if (g[e] > g0v) { g0v = g[e]; e0 = e; }
    float g1v = -1.f;
#pragma unroll
    for (int e = 0; e < Ee; e++) if (e != e0 && g[e] > g1v) { g1v = g[e]; e1 = e; }
    g2[t * 2 + 0] = g0v * inv;
    g2[t * 2 + 1] = g1v * inv;
    p0 = atomicAdd(&cnt[e0], 1);
    list[e0 * Tt + p0] = t * 2;
    p1 = atomicAdd(&cnt[e1], 1);
    list[e1 * Tt + p1] = t * 2 + 1;
  }
  e0 = __shfl(e0, 0); p0 = __shfl(p0, 0);
  e1 = __shfl(e1, 0); p1 = __shfl(p1, 0);
  ushort4* r0 = (ushort4*)(xg + ((size_t)e0 * Tt + p0) * Dd);
  ushort4* r1 = (ushort4*)(xg + ((size_t)e1 * Tt + p1) * Dd);
  const float4* x4 = reinterpret_cast<const float4*>(xr);
  for (int c = lane; c < Dd / 4; c += 64) {
    float4 v = x4[c];
    ushort4 o;
    o.x = f2bf_bits(v.x);
    o.y = f2bf_bits(v.y);
    o.z = f2bf_bits(v.z);
    o.w = f2bf_bits(v.w);
    r0[c] = o;
    r1[c] = o;
  }
}

// meta: [0..7]=row offs, [8..15]=m_e=ceil(ce/256), [16]=t1 tiles (gemm1), [17]=t2 (gemm2 x splitK2)
__global__ void scan_kernel(const int* __restrict__ cnt, int* __restrict__ meta) {
  if (threadIdx.x == 0 && blockIdx.x == 0) {
    int a = 0, t1 = 0, t2 = 0;
    for (int e = 0; e < Ee; e++) {
      meta[e] = a; a += cnt[e];
      int m = (cnt[e] + 255) >> 8;
      meta[8 + e] = m;
      t1 += m * (Hh / 256);        // 16 nt
      t2 += m * (Dd / 256) * 2;    // 4 nt x 2 splitK
    }
    meta[16] = t1;
    meta[17] = t2;
  }
}

// m204 bijective XCD chunk map.
__device__ __forceinline__ int xcd_map(int bid, int total, bool& ok) {
  int q = total >> 3, r8 = total & 7;
  int xcd = bid & 7, pos = bid >> 3;
  int cap = q + (xcd < r8 ? 1 : 0);
  ok = pos < cap;
  return (xcd < r8 ? xcd * (q + 1) : r8 * (q + 1) + (xcd - r8) * q) + pos;
}

// ============ 256x256 tile, BK=32, 8 waves (2Mx4N), 4-slot deep pipeline ============
// LDS slot per operand: [row(256)][32 elems] = 16 KB; 4 slots x (A+B) = 128 KB.
// Pipeline: prologue stages tiles 0,1,2 (4 glds/tile/thread); loop kt: vmcnt(8)
// [tile kt landed; 2 tiles in flight] -> lgkmcnt(0) -> barrier -> stage kt+3 into
// slot (kt+3)&3 (== slot (kt-1)&3, whose readers all passed this barrier) -> compute.
// Cover = 2 full tile-computes (~1280 cy) > HBM latency. Never drains in-loop.
// Swizzle (both sides): source granule (lane&3)^((lane>>2)&3); read granule kq^(fr&3).

#define SLOT 8192

#define STAGEK(arr_s, sl, kt3)                                            \
  do {                                                                    \
    int k0_ = (kt3) * 32;                                                 \
    glds16(aS0 + k0_, &As[(sl) * SLOT + w512]);                           \
    glds16(aS1 + k0_, &As[(sl) * SLOT + w512 + 4096]);                    \
    glds16(bS0 + k0_, &Bs[(sl) * SLOT + w512]);                           \
    glds16(bS1 + k0_, &Bs[(sl) * SLOT + w512 + 4096]);                    \
  } while (0)

#define COMPUTE(sl)                                                       \
  do {                                                                    \
    const short* Ab_ = &As[(sl) * SLOT];                                  \
    const short* Bb_ = &Bs[(sl) * SLOT];                                  \
    short8 af[8], bv[4];                                                  \
    _Pragma("unroll") for (int i = 0; i < 8; i++)                         \
        af[i] = *reinterpret_cast<const short8*>(                         \
            &Ab_[(wm * 128 + i * 16 + fr) * 32 + gph]);                   \
    _Pragma("unroll") for (int j = 0; j < 4; j++)                         \
        bv[j] = *reinterpret_cast<const short8*>(                         \
            &Bb_[(wn * 64 + j * 16 + fr) * 32 + gph]);                    \
    __builtin_amdgcn_s_setprio(1);                                        \
    _Pragma("unroll") for (int i = 0; i < 8; i++)                         \
      _Pragma("unroll") for (int j = 0; j < 4; j++)                       \
          acc[i][j] = __builtin_amdgcn_mfma_f32_16x16x32_bf16(af[i], bv[j], \
                                                              acc[i][j], 0, 0, 0); \
    __builtin_amdgcn_s_setprio(0);                                        \
  } while (0)

#define PIPELINE(NKT)                                                     \
  do {                                                                    \
    STAGEK(As, 0, 0);                                                     \
    STAGEK(As, 1, 1);                                                     \
    STAGEK(As, 2, 2);                                                     \
    for (int kt = 0; kt < (NKT); ++kt) {                                  \
      int sl = kt & 3;                                                    \
      if (kt <= (NKT)-3)                                                  \
        asm volatile("s_waitcnt vmcnt(8)" ::: "memory");                  \
      else if (kt == (NKT)-2)                                             \
        asm volatile("s_waitcnt vmcnt(4)" ::: "memory");                  \
      else                                                                \
        asm volatile("s_waitcnt vmcnt(0)" ::: "memory");                  \
      asm volatile("s_waitcnt lgkmcnt(0)" ::: "memory");                  \
      __builtin_amdgcn_s_barrier();                                       \
      if (kt + 3 < (NKT)) STAGEK(As, (kt + 3) & 3, kt + 3);               \
      COMPUTE(sl);                                                        \
    }                                                                     \
  } while (0)

// ---------------- GEMM1: h = gelu(xg @ W1[e]^T + b1[e]) -> bf16 ----------------
__global__ __launch_bounds__(512, 2) void gemm1_kernel(
    const unsigned short* __restrict__ xg, const unsigned short* __restrict__ w1b,
    const float* __restrict__ b1,
    const int* __restrict__ cnt, const int* __restrict__ meta,
    unsigned short* __restrict__ hb) {
  bool ok;
  int idx = xcd_map(blockIdx.x, meta[16], ok);
  if (!ok) return;
  int e = 0, base = 0;
  for (;;) {
    int span = meta[8 + e] * (Hh / 256);
    if (idx < base + span) break;
    base += span; ++e;
  }
  int r = idx - base, m_e = meta[8 + e];
  int nt = r / m_e, mt = r % m_e;     // mt-inner: consecutive idx share the B-panel
  int ce = cnt[e], off_e = meta[e];

  __shared__ short As[4 * SLOT];
  __shared__ short Bs[4 * SLOT];

  int tid = threadIdx.x;
  int lane = tid & 63;
  int w = tid >> 6;                   // 0..7
  int wm = w >> 2, wn = w & 3;        // 2M x 4N
  int fr = lane & 15, kq = lane >> 4;
  int w512 = w * 512;
  int gph = (kq ^ (fr & 3)) * 8;

  int srow = w * 16 + (lane >> 2);                    // staging row 0..127 (p adds 128)
  int swz = ((lane & 3) ^ ((lane >> 2) & 3)) * 8;     // source granule pre-swizzle
  const unsigned short* aS0 = xg + ((size_t)e * Tt + mt * 256 + srow) * Dd + swz;
  const unsigned short* aS1 = aS0 + (size_t)128 * Dd;
  const unsigned short* bS0 = w1b + (size_t)e * Hh * Dd + (size_t)(nt * 256 + srow) * Dd + swz;
  const unsigned short* bS1 = bS0 + (size_t)128 * Dd;

  // Preload epilogue bias, then drain so pipeline vmcnt counts stay exact.
  float biasj[4];
#pragma unroll
  for (int j = 0; j < 4; j++) biasj[j] = b1[(size_t)e * Hh + nt * 256 + wn * 64 + j * 16 + fr];
  asm volatile("s_waitcnt vmcnt(0)" ::: "memory");

  f32x4 acc[8][4] = {};
  PIPELINE(Dd / 32);   // 32 K-tiles

#pragma unroll
  for (int i = 0; i < 8; i++) {
    int rb = wm * 128 + i * 16 + kq * 4;
#pragma unroll
    for (int j = 0; j < 4; j++) {
      int col = nt * 256 + wn * 64 + j * 16 + fr;
#pragma unroll
      for (int rr = 0; rr < 4; rr++) {
        int grow = mt * 256 + rb + rr;
        if (grow < ce) {
          float v = acc[i][j][rr] + biasj[j];
          v = 0.5f * v * (1.0f + erff(v * 0.70710678118654752f));
          hb[(size_t)(off_e + grow) * Hh + col] = f2bf_bits(v);
        }
      }
    }
  }
}

// ---------------- GEMM2: out[t] += g * (h @ W2[e]^T + b2[e]), split-K=2, atomic ----------
__global__ __launch_bounds__(512, 2) void gemm2_kernel(
    const unsigned short* __restrict__ hb, const unsigned short* __restrict__ w2b,
    const float* __restrict__ b2,
    const int* __restrict__ cnt, const int* __restrict__ meta, const int* __restrict__ list,
    const float* __restrict__ g2, float* __restrict__ out) {
  bool ok;
  int idx = xcd_map(blockIdx.x, meta[17], ok);
  if (!ok) return;
  int e = 0, base = 0;
  for (;;) {
    int span = meta[8 + e] * (Dd / 256) * 2;
    if (idx < base + span) break;
    base += span; ++e;
  }
  int r = idx - base, m_e = meta[8 + e];
  int g = r / m_e, mt = r % m_e;      // mt-inner within each (nt,ks) group
  int nt = g >> 1, ks = g & 1;
  int ce = cnt[e], off_e = meta[e];

  __shared__ short As[4 * SLOT];
  __shared__ short Bs[4 * SLOT];

  int tid = threadIdx.x;
  int lane = tid & 63;
  int w = tid >> 6;
  int wm = w >> 2, wn = w & 3;
  int fr = lane & 15, kq = lane >> 4;
  int w512 = w * 512;
  int gph = (kq ^ (fr & 3)) * 8;

  int srow = w * 16 + (lane >> 2);
  int swz = ((lane & 3) ^ ((lane >> 2) & 3)) * 8;
  // Per-half row clamp keeps A reads inside expert e's hb region (rows >= ce unused).
  int ra0 = mt * 256 + srow;       if (ra0 >= ce) ra0 = ce - 1;
  int ra1 = mt * 256 + srow + 128; if (ra1 >= ce) ra1 = ce - 1;
  const unsigned short* aS0 = hb + (size_t)(off_e + ra0) * Hh + ks * 2048 + swz;
  const unsigned short* aS1 = hb + (size_t)(off_e + ra1) * Hh + ks * 2048 + swz;
  const unsigned short* bS0 = w2b + (size_t)e * Dd * Hh + (size_t)(nt * 256 + srow) * Hh + ks * 2048 + swz;
  const unsigned short* bS1 = bS0 + (size_t)128 * Hh;

  float bsc = (ks == 0) ? 1.f : 0.f;
  float biasj[4];
#pragma unroll
  for (int j = 0; j < 4; j++)
    biasj[j] = b2[(size_t)e * Dd + nt * 256 + wn * 64 + j * 16 + fr] * bsc;
  asm volatile("s_waitcnt vmcnt(0)" ::: "memory");

  f32x4 acc[8][4] = {};
  PIPELINE(2048 / 32);   // 64 K-tiles per split

  const int* le = list + e * Tt;
#pragma unroll
  for (int i = 0; i < 8; i++) {
    int rb = wm * 128 + i * 16 + kq * 4;
#pragma unroll
    for (int j = 0; j < 4; j++) {
      int col = nt * 256 + wn * 64 + j * 16 + fr;
#pragma unroll
      for (int rr = 0; rr < 4; rr++) {
        int grow = mt * 256 + rb + rr;
        if (grow < ce) {
          int en = le[grow];
          float v = (acc[i][j][rr] + biasj[j]) * g2[en];
          unsafeAtomicAdd(&out[(size_t)(en >> 1) * Dd + col], v);
        }
      }
    }
  }
}

extern "C" void kernel_launch(void* const* d_in, const int* in_sizes, int n_in,
                              void* d_out, int out_size, void* d_ws, size_t ws_size,
                              hipStream_t stream) {
  const float* x  = (const float*)d_in[0];
  const float* Wr = (const float*)d_in[1];
  const float* br = (const float*)d_in[2];
  const float* W1 = (const float*)d_in[3];
  const float* b1 = (const float*)d_in[4];
  const float* W2 = (const float*)d_in[5];
  const float* b2 = (const float*)d_in[6];
  float* out = (float*)d_out;

  char* base = (char*)d_ws;
  size_t o = 0;
  auto alloc = [&](size_t n) { char* r = base + o; o += (n + 255) & ~(size_t)255; return r; };
  unsigned short* w1b = (unsigned short*)alloc((size_t)Ee * Hh * Dd * 2);
  unsigned short* w2b = (unsigned short*)alloc((size_t)Ee * Dd * Hh * 2);
  unsigned short* xg  = (unsigned short*)alloc((size_t)Ee * Tt * Dd * 2);
  unsigned short* hb  = (unsigned short*)alloc((size_t)Tt * Kk * Hh * 2);
  int* list  = (int*)alloc((size_t)Ee * Tt * 4);
  float* g2  = (float*)alloc((size_t)Tt * Kk * 4);
  int* cnt   = (int*)alloc(Ee * 4);
  int* meta  = (int*)alloc(32 * 4);
  if (o > ws_size) return;  // workspace too small: fail loudly (output stays poisoned)

  hipMemsetAsync(cnt, 0, Ee * 4, stream);
  hipMemsetAsync(out, 0, (size_t)out_size * 4, stream);

  cvt_kernel<<<4096, 256, 0, stream>>>(W1, w1b, Ee * Hh * Dd / 4);
  cvt_kernel<<<4096, 256, 0, stream>>>(W2, w2b, Ee * Dd * Hh / 4);

  router_kernel<<<Tt / 4, 256, 0, stream>>>(x, Wr, br, cnt, list, g2, xg);
  scan_kernel<<<1, 64, 0, stream>>>(cnt, meta);

  // worst-case tiles: sum(ceil(ce/256)) <= 8192/256 + 7 = 39 -> t1<=624, t2<=312
  gemm1_kernel<<<632, 512, 0, stream>>>(xg, w1b, b1, cnt, meta, hb);
  gemm2_kernel<<<320, 512, 0, stream>>>(hb, w2b, b2, cnt, meta, list, g2, out);
}

// Round 11
// 576.903 us; speedup vs baseline: 1.2551x; 1.2551x over previous
//
#include <hip/hip_runtime.h>
#include <hip/hip_bf16.h>

#define Dd 1024
#define Hh 4096
#define Ee 8
#define Tt 4096   // tokens = 2*2048
#define Kk 2

typedef __attribute__((ext_vector_type(8))) short short8;
typedef __attribute__((ext_vector_type(4))) float f32x4;

__device__ __forceinline__ unsigned short f2bf_bits(float f) {
  unsigned u = __builtin_bit_cast(unsigned, f);
  u += 0x7FFFu + ((u >> 16) & 1u);   // RNE (finite values)
  return (unsigned short)(u >> 16);
}

__device__ __forceinline__ void glds16(const void* g, void* l) {
  __builtin_amdgcn_global_load_lds(
      (const __attribute__((address_space(1))) unsigned int*)g,
      (__attribute__((address_space(3))) unsigned int*)l, 16, 0, 0);
}

// ---------------- fp32 -> bf16 conversion (vectorized) ----------------
__global__ __launch_bounds__(256) void cvt_kernel(const float* __restrict__ src,
                                                  unsigned short* __restrict__ dst, int n4) {
  int i = blockIdx.x * blockDim.x + threadIdx.x;
  int stride = gridDim.x * blockDim.x;
  for (; i < n4; i += stride) {
    float4 v = reinterpret_cast<const float4*>(src)[i];
    ushort4 o;
    o.x = f2bf_bits(v.x);
    o.y = f2bf_bits(v.y);
    o.z = f2bf_bits(v.z);
    o.w = f2bf_bits(v.w);
    reinterpret_cast<ushort4*>(dst)[i] = o;
  }
}

// ---------------- router: softmax + top-2 + expert lists + fused token gather ----------------
__global__ __launch_bounds__(256) void router_kernel(
    const float* __restrict__ x, const float* __restrict__ Wr, const float* __restrict__ br,
    int* __restrict__ cnt, int* __restrict__ list, float* __restrict__ g2,
    unsigned short* __restrict__ xg) {
  int t = blockIdx.x * 4 + (threadIdx.x >> 6);
  int lane = threadIdx.x & 63;
  const float* xr = x + (size_t)t * Dd;
  float pe[Ee];
#pragma unroll
  for (int e = 0; e < Ee; e++) pe[e] = 0.f;
  for (int d = lane; d < Dd; d += 64) {
    float xv = xr[d];
#pragma unroll
    for (int e = 0; e < Ee; e++) pe[e] += xv * Wr[e * Dd + d];
  }
#pragma unroll
  for (int e = 0; e < Ee; e++) {
    float v = pe[e];
#pragma unroll
    for (int s = 32; s > 0; s >>= 1) v += __shfl_xor(v, s);
    pe[e] = v + br[e];
  }
  int e0 = 0, e1 = 0, p0 = 0, p1 = 0;
  if (lane == 0) {
    float mx = pe[0];
#pragma unroll
    for (int e = 1; e < Ee; e++) mx = fmaxf(mx, pe[e]);
    float g[Ee];
    float sum = 0.f;
#pragma unroll
    for (int e = 0; e < Ee; e++) { g[e] = expf(pe[e] - mx); sum += g[e]; }
    float inv = 1.0f / sum;
    float g0v = g[0];
#pragma unroll
    for (int e = 1; e < Ee; e++) if (g[e] > g0v) { g0v = g[e]; e0 = e; }
    float g1v = -1.f;
#pragma unroll
    for (int e = 0; e < Ee; e++) if (e != e0 && g[e] > g1v) { g1v = g[e]; e1 = e; }
    g2[t * 2 + 0] = g0v * inv;
    g2[t * 2 + 1] = g1v * inv;
    p0 = atomicAdd(&cnt[e0], 1);
    list[e0 * Tt + p0] = t * 2;
    p1 = atomicAdd(&cnt[e1], 1);
    list[e1 * Tt + p1] = t * 2 + 1;
  }
  e0 = __shfl(e0, 0); p0 = __shfl(p0, 0);
  e1 = __shfl(e1, 0); p1 = __shfl(p1, 0);
  ushort4* r0 = (ushort4*)(xg + ((size_t)e0 * Tt + p0) * Dd);
  ushort4* r1 = (ushort4*)(xg + ((size_t)e1 * Tt + p1) * Dd);
  const float4* x4 = reinterpret_cast<const float4*>(xr);
  for (int c = lane; c < Dd / 4; c += 64) {
    float4 v = x4[c];
    ushort4 o;
    o.x = f2bf_bits(v.x);
    o.y = f2bf_bits(v.y);
    o.z = f2bf_bits(v.z);
    o.w = f2bf_bits(v.w);
    r0[c] = o;
    r1[c] = o;
  }
}

// meta: [0..7]=row offs, [8..15]=m_e=ceil(ce/128)
__global__ void scan_kernel(const int* __restrict__ cnt, int* __restrict__ meta) {
  if (threadIdx.x == 0 && blockIdx.x == 0) {
    int a = 0;
    for (int e = 0; e < Ee; e++) {
      meta[e] = a; a += cnt[e];
      meta[8 + e] = (cnt[e] + 127) >> 7;
    }
  }
}

// ================== 128x128 tile, BK=64, 4 waves (2x2) ==================
// r9-proven layout: LDS [row(128)][64 elems], 128-B rows; staging 8 lanes/row
// (fully-used 64B lines); both-sides swizzle: source granule (lane&7)^(row&7),
// read granule (kk*4+kq)^(fr&7). 0 bank conflicts measured (r9).
// 2-buffer counted pipeline: STAGE(kt+2) issued 2 iterations ahead; in-loop
// vmcnt(8) (one tile in flight), never drained.

#define STAGE(so_, k0)                                                          \
  do {                                                                          \
    _Pragma("unroll") for (int p = 0; p < 4; p++) {                             \
      glds16(aS + (size_t)p * 32 * SK + (k0), AsW + (so_) * 8192 + p * 2048);   \
      glds16(bS + (size_t)p * 32 * SK + (k0), BsW + (so_) * 8192 + p * 2048);   \
    }                                                                           \
  } while (0)

#define COMPUTE(so_)                                                            \
  do {                                                                          \
    _Pragma("unroll") for (int s = 0; s < 2; s++) {                             \
      int gg = (g0 ^ (s << 2)) << 3;                                            \
      short8 af[4], bv[4];                                                      \
      _Pragma("unroll") for (int i = 0; i < 4; i++)                             \
          af[i] = *reinterpret_cast<const short8*>(                             \
              &As[(so_) * 8192 + aoff + i * 1024 + gg]);                        \
      _Pragma("unroll") for (int j = 0; j < 4; j++)                             \
          bv[j] = *reinterpret_cast<const short8*>(                             \
              &Bs[(so_) * 8192 + boff + j * 1024 + gg]);                        \
      __builtin_amdgcn_s_setprio(1);                                            \
      _Pragma("unroll") for (int i = 0; i < 4; i++)                             \
        _Pragma("unroll") for (int j = 0; j < 4; j++)                           \
            acc[i][j] = __builtin_amdgcn_mfma_f32_16x16x32_bf16(af[i], bv[j],   \
                                                                acc[i][j], 0, 0, 0); \
      __builtin_amdgcn_s_setprio(0);                                            \
    }                                                                           \
  } while (0)

#define PIPELINE(NKT)                                              \
  do {                                                             \
    STAGE(0, 0);                                                   \
    STAGE(1, 64);                                                  \
    for (int kt = 0; kt <= (NKT)-3; ++kt) {                        \
      int so = kt & 1;                                             \
      asm volatile("s_waitcnt vmcnt(8)" ::: "memory");             \
      __builtin_amdgcn_s_barrier();                                \
      COMPUTE(so);                                                 \
      __builtin_amdgcn_s_barrier();                                \
      STAGE(so, (kt + 2) * 64);                                    \
    }                                                              \
    asm volatile("s_waitcnt vmcnt(8)" ::: "memory");               \
    __builtin_amdgcn_s_barrier();                                  \
    COMPUTE(((NKT)-2) & 1);                                        \
    asm volatile("s_waitcnt vmcnt(0)" ::: "memory");               \
    __builtin_amdgcn_s_barrier();                                  \
    COMPUTE(((NKT)-1) & 1);                                        \
  } while (0)

// ---------------- GEMM1: h = gelu(xg @ W1[e]^T + b1[e]) -> bf16 ----------------
// Expert->XCD affinity: e = bid&7 (empirical bid%8 -> XCD); per-expert grid-stride
// over the dense local tile list (mt-inner: consecutive locals share the B-panel,
// and run concurrently on the SAME XCD -> panel hot in that L2; xg[e] ~2MB also
// L2-resident). No dead blocks, no cross-XCD panel duplication.
__global__ __launch_bounds__(256, 2) void gemm1_kernel(
    const unsigned short* __restrict__ xg, const unsigned short* __restrict__ w1b,
    const float* __restrict__ b1,
    const int* __restrict__ cnt, const int* __restrict__ meta,
    unsigned short* __restrict__ hb) {
  int e = blockIdx.x & 7;
  int G = gridDim.x >> 3;
  int m_e = meta[8 + e];
  int ce = cnt[e], off_e = meta[e];
  int span = m_e * (Hh / 128);

  __shared__ short As[2 * 8192];
  __shared__ short Bs[2 * 8192];

  const int SK = Dd;
  int tid = threadIdx.x;
  int lane = tid & 63;
  int w = tid >> 6;
  int wm = w >> 1, wn = w & 1;
  int fr = lane & 15, kq = lane >> 4;

  int rbase = w * 8 + (lane >> 3);               // staging row within 32-row stripe
  int swz = ((lane & 7) ^ (rbase & 7)) << 3;     // source granule pre-swizzle
  short* AsW = &As[w * 512];
  short* BsW = &Bs[w * 512];
  int aoff = (wm * 64 + fr) * 64;
  int boff = (wn * 64 + fr) * 64;
  int g0 = kq ^ (fr & 7);
  const float* b1e = b1 + (size_t)e * Hh;

  for (int local = blockIdx.x >> 3; local < span; local += G) {
    int nt = local / m_e, mt = local % m_e;

    __syncthreads();   // previous tile's LDS readers done before re-staging

    const unsigned short* aS = xg + (size_t)e * Tt * Dd + (size_t)(mt * 128 + rbase) * SK + swz;
    const unsigned short* bS = w1b + (size_t)e * Hh * Dd + (size_t)(nt * 128 + rbase) * SK + swz;

    float biasj[4];
#pragma unroll
    for (int j = 0; j < 4; j++) biasj[j] = b1e[nt * 128 + wn * 64 + j * 16 + fr];
    asm volatile("s_waitcnt vmcnt(0)" ::: "memory");

    f32x4 acc[4][4] = {};
    PIPELINE(Dd / 64);   // 16 K-steps

#pragma unroll
    for (int i = 0; i < 4; i++) {
      int rb = wm * 64 + i * 16 + kq * 4;
#pragma unroll
      for (int j = 0; j < 4; j++) {
        int col = nt * 128 + wn * 64 + j * 16 + fr;
#pragma unroll
        for (int rr = 0; rr < 4; rr++) {
          int grow = mt * 128 + rb + rr;
          if (grow < ce) {
            float v = acc[i][j][rr] + biasj[j];
            v = 0.5f * v * (1.0f + erff(v * 0.70710678118654752f));
            hb[(size_t)(off_e + grow) * Hh + col] = f2bf_bits(v);
          }
        }
      }
    }
  }
}

// ---------------- GEMM2: out[t] += g * (h @ W2[e]^T + b2[e]), split-K=2, atomic ----------
// Same expert->XCD affinity: hb[e] was written by THIS XCD's gemm1 -> L2/L3-warm.
__global__ __launch_bounds__(256, 2) void gemm2_kernel(
    const unsigned short* __restrict__ hb, const unsigned short* __restrict__ w2b,
    const float* __restrict__ b2,
    const int* __restrict__ cnt, const int* __restrict__ meta, const int* __restrict__ list,
    const float* __restrict__ g2, float* __restrict__ out) {
  int e = blockIdx.x & 7;
  int G = gridDim.x >> 3;
  int m_e = meta[8 + e];
  int ce = cnt[e], off_e = meta[e];
  int span = m_e * (Dd / 128) * 2;

  __shared__ short As[2 * 8192];
  __shared__ short Bs[2 * 8192];

  const int SK = Hh;
  int tid = threadIdx.x;
  int lane = tid & 63;
  int w = tid >> 6;
  int wm = w >> 1, wn = w & 1;
  int fr = lane & 15, kq = lane >> 4;

  int rbase = w * 8 + (lane >> 3);
  int swz = ((lane & 7) ^ (rbase & 7)) << 3;
  short* AsW = &As[w * 512];
  short* BsW = &Bs[w * 512];
  int aoff = (wm * 64 + fr) * 64;
  int boff = (wn * 64 + fr) * 64;
  int g0 = kq ^ (fr & 7);
  const float* b2e = b2 + (size_t)e * Dd;
  const int* le = list + e * Tt;

  for (int local = blockIdx.x >> 3; local < span; local += G) {
    int g = local / m_e, mt = local % m_e;   // mt-inner within each (nt,ks) group
    int nt = g >> 1, ks = g & 1;

    __syncthreads();

    int ra = mt * 128 + rbase; if (ra >= ce) ra = ce - 1;   // clamp (address safety only)
    const unsigned short* aS = hb + (size_t)(off_e + ra) * SK + ks * 2048 + swz;
    const unsigned short* bS = w2b + (size_t)e * Dd * Hh + (size_t)(nt * 128 + rbase) * SK + ks * 2048 + swz;

    float bsc = (ks == 0) ? 1.f : 0.f;
    float biasj[4];
#pragma unroll
    for (int j = 0; j < 4; j++)
      biasj[j] = b2e[nt * 128 + wn * 64 + j * 16 + fr] * bsc;
    asm volatile("s_waitcnt vmcnt(0)" ::: "memory");

    f32x4 acc[4][4] = {};
    PIPELINE(2048 / 64);   // 32 K-steps per split

#pragma unroll
    for (int i = 0; i < 4; i++) {
      int rb = wm * 64 + i * 16 + kq * 4;
#pragma unroll
      for (int j = 0; j < 4; j++) {
        int col = nt * 128 + wn * 64 + j * 16 + fr;
#pragma unroll
        for (int rr = 0; rr < 4; rr++) {
          int grow = mt * 128 + rb + rr;
          if (grow < ce) {
            int en = le[grow];
            float v = (acc[i][j][rr] + biasj[j]) * g2[en];
            unsafeAtomicAdd(&out[(size_t)(en >> 1) * Dd + col], v);
          }
        }
      }
    }
  }
}

extern "C" void kernel_launch(void* const* d_in, const int* in_sizes, int n_in,
                              void* d_out, int out_size, void* d_ws, size_t ws_size,
                              hipStream_t stream) {
  const float* x  = (const float*)d_in[0];
  const float* Wr = (const float*)d_in[1];
  const float* br = (const float*)d_in[2];
  const float* W1 = (const float*)d_in[3];
  const float* b1 = (const float*)d_in[4];
  const float* W2 = (const float*)d_in[5];
  const float* b2 = (const float*)d_in[6];
  float* out = (float*)d_out;

  char* base = (char*)d_ws;
  size_t o = 0;
  auto alloc = [&](size_t n) { char* r = base + o; o += (n + 255) & ~(size_t)255; return r; };
  unsigned short* w1b = (unsigned short*)alloc((size_t)Ee * Hh * Dd * 2);
  unsigned short* w2b = (unsigned short*)alloc((size_t)Ee * Dd * Hh * 2);
  unsigned short* xg  = (unsigned short*)alloc((size_t)Ee * Tt * Dd * 2);
  unsigned short* hb  = (unsigned short*)alloc((size_t)Tt * Kk * Hh * 2);
  int* list  = (int*)alloc((size_t)Ee * Tt * 4);
  float* g2  = (float*)alloc((size_t)Tt * Kk * 4);
  int* cnt   = (int*)alloc(Ee * 4);
  int* meta  = (int*)alloc(32 * 4);
  if (o > ws_size) return;  // workspace too small: fail loudly (output stays poisoned)

  hipMemsetAsync(cnt, 0, Ee * 4, stream);
  hipMemsetAsync(out, 0, (size_t)out_size * 4, stream);

  cvt_kernel<<<4096, 256, 0, stream>>>(W1, w1b, Ee * Hh * Dd / 4);
  cvt_kernel<<<4096, 256, 0, stream>>>(W2, w2b, Ee * Dd * Hh / 4);

  router_kernel<<<Tt / 4, 256, 0, stream>>>(x, Wr, br, cnt, list, g2, xg);
  scan_kernel<<<1, 64, 0, stream>>>(cnt, meta);

  // 8 XCD-groups x G blocks; grid-stride covers any expert skew
  gemm1_kernel<<<8 * 256, 256, 0, stream>>>(xg, w1b, b1, cnt, meta, hb);
  gemm2_kernel<<<8 * 128, 256, 0, stream>>>(hb, w2b, b2, cnt, meta, list, g2, out);
}